// Round 2
// baseline (75.839 us; speedup 1.0000x reference)
//
#include <hip/hip_runtime.h>
#include <stdint.h>

// Contrastive loss: B=16384, C=1000, D=128, fp32 in, scalar fp32 out.
// dist = f2 + c2 - 2*cross; loss = sum(relu(1-dist) over j!=target)/B.
//
// Structure (round 2): no LDS anywhere.
//  - prep_kernel: cls fp32 -> bf16 in MFMA-fragment order into d_ws (zero-
//    padded to 1024 cols), c2[1024] into d_ws, zero d_out. 64 blocks x 1 wave.
//  - closs_kernel: grid (4,256), 256 thr (4 waves). Each wave owns 16 rows x
//    256 cols. A fragments global->reg with inline convert; f2 in-reg via
//    shuffles; inner loop = 4 coalesced B-frag loads + 4 MFMA + hinge; one
//    atomicAdd per wave at the end.
#define B_N 16384
#define C_N 1000
#define D_N 128
#define NB_TOT 64          // 1024 padded columns / 16
#define MARGIN 1.0f

typedef __attribute__((ext_vector_type(8))) short short8;  // 8 bf16
typedef __attribute__((ext_vector_type(4))) float f32x4;   // MFMA acc

__device__ __forceinline__ short f2bf(float f) {
    union { float f; uint32_t u; } v; v.f = f;
    uint32_t u = v.u;
    return (short)((u + 0x7FFFu + ((u >> 16) & 1u)) >> 16);
}

__device__ __forceinline__ short8 cvt8(const float4& v0, const float4& v1) {
    short8 s;
    s[0] = f2bf(v0.x); s[1] = f2bf(v0.y); s[2] = f2bf(v0.z); s[3] = f2bf(v0.w);
    s[4] = f2bf(v1.x); s[5] = f2bf(v1.y); s[6] = f2bf(v1.z); s[7] = f2bf(v1.w);
    return s;
}

// ---- kernel 1: relayout classes to fragment order + c2 + zero out ----
// Fragment (nb, kk) for the 16x16x32 bf16 MFMA: lane (l15,kg) holds
// cls[nb*16+l15][kk*32+kg*8 .. +8]. Stored at ((nb*4+kk)*64+lane)*8 shorts,
// so kernel 2's per-wave frag load is 64 consecutive 16B chunks = 1 KB.
__global__ __launch_bounds__(64) void prep_kernel(
    const float* __restrict__ cls, short* __restrict__ bpre,
    float* __restrict__ c2p, float* __restrict__ out)
{
    const int nb   = blockIdx.x;       // 0..63
    const int lane = threadIdx.x;      // 0..63
    const int l15  = lane & 15;
    const int kg   = lane >> 4;
    const int col  = nb * 16 + l15;
    const bool valid = col < C_N;

    float sq = 0.f;
    #pragma unroll
    for (int kk = 0; kk < 4; ++kk) {
        float4 v0 = make_float4(0.f, 0.f, 0.f, 0.f);
        float4 v1 = make_float4(0.f, 0.f, 0.f, 0.f);
        if (valid) {
            const float* p = cls + (size_t)col * D_N + kk * 32 + kg * 8;
            v0 = *reinterpret_cast<const float4*>(p);
            v1 = *reinterpret_cast<const float4*>(p + 4);
        }
        sq += v0.x*v0.x + v0.y*v0.y + v0.z*v0.z + v0.w*v0.w
            + v1.x*v1.x + v1.y*v1.y + v1.z*v1.z + v1.w*v1.w;
        *reinterpret_cast<short8*>(bpre + ((size_t)(nb * 4 + kk) * 64 + lane) * 8)
            = cvt8(v0, v1);
    }
    sq += __shfl_xor(sq, 16);
    sq += __shfl_xor(sq, 32);
    if (lane < 16) c2p[nb * 16 + lane] = valid ? sq : 0.f;
    if (nb == 0 && lane == 0) out[0] = 0.f;
}

// ---- kernel 2: the fused GEMM + hinge ----
__global__ __launch_bounds__(256, 4) void closs_kernel(
    const float* __restrict__ feat, const int* __restrict__ tgt,
    const short* __restrict__ bpre, const float* __restrict__ c2p,
    float* __restrict__ out)
{
    const int tid  = threadIdx.x;
    const int wave = tid >> 6;
    const int lane = tid & 63;
    const int l15  = lane & 15;
    const int kg   = lane >> 4;
    const int row0 = blockIdx.y * 64 + wave * 16;   // wave's 16-row base
    const int nb0  = blockIdx.x * (NB_TOT / 4);     // 16 col-blocks per block

    // A fragments (16 rows x K=128) straight into registers, + f2 on the fly.
    short8 a[4];
    float sq = 0.f;
    const float* ap = feat + (size_t)(row0 + l15) * D_N + kg * 8;
    #pragma unroll
    for (int kk = 0; kk < 4; ++kk) {
        float4 v0 = *reinterpret_cast<const float4*>(ap + kk * 32);
        float4 v1 = *reinterpret_cast<const float4*>(ap + kk * 32 + 4);
        sq += v0.x*v0.x + v0.y*v0.y + v0.z*v0.z + v0.w*v0.w
            + v1.x*v1.x + v1.y*v1.y + v1.z*v1.z + v1.w*v1.w;
        a[kk] = cvt8(v0, v1);
    }
    // full row-f2 (row l15) in every lane, then pick up the 4 acc rows.
    sq += __shfl_xor(sq, 16);
    sq += __shfl_xor(sq, 32);
    float f2r[4]; int tg[4];
    #pragma unroll
    for (int r = 0; r < 4; ++r) {
        f2r[r] = __shfl(sq, kg * 4 + r);
        tg[r]  = tgt[row0 + kg * 4 + r];
    }

    float hsum = 0.f;
    #pragma unroll 4
    for (int i = 0; i < NB_TOT / 4; ++i) {
        const int nb = nb0 + i;
        const short8* bp =
            reinterpret_cast<const short8*>(bpre + (size_t)nb * 4 * 64 * 8) + lane;
        short8 b0 = bp[0];
        short8 b1 = bp[64];
        short8 b2 = bp[128];
        short8 b3 = bp[192];
        f32x4 acc = (f32x4){0.f, 0.f, 0.f, 0.f};
        acc = __builtin_amdgcn_mfma_f32_16x16x32_bf16(a[0], b0, acc, 0, 0, 0);
        acc = __builtin_amdgcn_mfma_f32_16x16x32_bf16(a[1], b1, acc, 0, 0, 0);
        acc = __builtin_amdgcn_mfma_f32_16x16x32_bf16(a[2], b2, acc, 0, 0, 0);
        acc = __builtin_amdgcn_mfma_f32_16x16x32_bf16(a[3], b3, acc, 0, 0, 0);
        // C/D layout: col = lane&15, row = kg*4 + r (verified m89).
        const int col   = nb * 16 + l15;
        const float c2v = c2p[col];
        #pragma unroll
        for (int r = 0; r < 4; ++r) {
            const float dist = f2r[r] + c2v - 2.0f * acc[r];
            float h = fmaxf(0.0f, MARGIN - dist);
            if (col >= C_N || col == tg[r]) h = 0.0f;
            hsum += h;
        }
    }
    hsum *= (1.0f / 16384.0f);
    #pragma unroll
    for (int off = 32; off; off >>= 1) hsum += __shfl_down(hsum, off);
    if (lane == 0) atomicAdd(out, hsum);
}

extern "C" void kernel_launch(void* const* d_in, const int* in_sizes, int n_in,
                              void* d_out, int out_size, void* d_ws, size_t ws_size,
                              hipStream_t stream) {
    const float* feat = (const float*)d_in[0];
    const int*   tgt  = (const int*)d_in[1];
    const float* cls  = (const float*)d_in[2];
    float*       out  = (float*)d_out;

    short* bpre = (short*)d_ws;                                 // 262144 B
    float* c2p  = (float*)((char*)d_ws + (size_t)NB_TOT * 4 * 64 * 8 * sizeof(short));

    prep_kernel<<<64, 64, 0, stream>>>(cls, bpre, c2p, out);
    closs_kernel<<<dim3(4, 256), 256, 0, stream>>>(feat, tgt, bpre, c2p, out);
}

// Round 3
// 26.422 us; speedup vs baseline: 2.8703x; 2.8703x over previous
//
#include <hip/hip_runtime.h>
#include <stdint.h>

// Contrastive loss: B=16384, C=1000, D=128, fp32 in, scalar fp32 out.
// dist = f2 + c2 - 2*cross; loss = sum(relu(1-dist) over j!=target)/B.
//
// Round 3: same body as round 2, but NO global atomics. Each block stores one
// partial to d_ws; a final 1-block kernel reduces 1024 partials into out[0].
// (Rounds 1+2 both stalled at ~68us with all pipes idle -> the shared
// single-address atomicAdd tail was the suspected serializer.)
#define B_N 16384
#define C_N 1000
#define D_N 128
#define NB_TOT 64          // 1024 padded columns / 16
#define MARGIN 1.0f
#define NBLK 1024          // closs grid size (4 x 256)

typedef __attribute__((ext_vector_type(8))) short short8;  // 8 bf16
typedef __attribute__((ext_vector_type(4))) float f32x4;   // MFMA acc

__device__ __forceinline__ short f2bf(float f) {
    union { float f; uint32_t u; } v; v.f = f;
    uint32_t u = v.u;
    return (short)((u + 0x7FFFu + ((u >> 16) & 1u)) >> 16);
}

__device__ __forceinline__ short8 cvt8(const float4& v0, const float4& v1) {
    short8 s;
    s[0] = f2bf(v0.x); s[1] = f2bf(v0.y); s[2] = f2bf(v0.z); s[3] = f2bf(v0.w);
    s[4] = f2bf(v1.x); s[5] = f2bf(v1.y); s[6] = f2bf(v1.z); s[7] = f2bf(v1.w);
    return s;
}

// ---- kernel 1: relayout classes to fragment order + c2 ----
// Fragment (nb, kk): lane (l15,kg) holds cls[nb*16+l15][kk*32+kg*8 .. +8].
__global__ __launch_bounds__(64) void prep_kernel(
    const float* __restrict__ cls, short* __restrict__ bpre,
    float* __restrict__ c2p)
{
    const int nb   = blockIdx.x;       // 0..63
    const int lane = threadIdx.x;      // 0..63
    const int l15  = lane & 15;
    const int kg   = lane >> 4;
    const int col  = nb * 16 + l15;
    const bool valid = col < C_N;

    float sq = 0.f;
    #pragma unroll
    for (int kk = 0; kk < 4; ++kk) {
        float4 v0 = make_float4(0.f, 0.f, 0.f, 0.f);
        float4 v1 = make_float4(0.f, 0.f, 0.f, 0.f);
        if (valid) {
            const float* p = cls + (size_t)col * D_N + kk * 32 + kg * 8;
            v0 = *reinterpret_cast<const float4*>(p);
            v1 = *reinterpret_cast<const float4*>(p + 4);
        }
        sq += v0.x*v0.x + v0.y*v0.y + v0.z*v0.z + v0.w*v0.w
            + v1.x*v1.x + v1.y*v1.y + v1.z*v1.z + v1.w*v1.w;
        *reinterpret_cast<short8*>(bpre + ((size_t)(nb * 4 + kk) * 64 + lane) * 8)
            = cvt8(v0, v1);
    }
    sq += __shfl_xor(sq, 16);
    sq += __shfl_xor(sq, 32);
    if (lane < 16) c2p[nb * 16 + lane] = valid ? sq : 0.f;
}

// ---- kernel 2: fused GEMM + hinge; one plain store per block ----
__global__ __launch_bounds__(256, 4) void closs_kernel(
    const float* __restrict__ feat, const int* __restrict__ tgt,
    const short* __restrict__ bpre, const float* __restrict__ c2p,
    float* __restrict__ part)
{
    const int tid  = threadIdx.x;
    const int wave = tid >> 6;
    const int lane = tid & 63;
    const int l15  = lane & 15;
    const int kg   = lane >> 4;
    const int row0 = blockIdx.y * 64 + wave * 16;   // wave's 16-row base
    const int nb0  = blockIdx.x * (NB_TOT / 4);     // 16 col-blocks per block

    // A fragments (16 rows x K=128) straight into registers, + f2 on the fly.
    short8 a[4];
    float sq = 0.f;
    const float* ap = feat + (size_t)(row0 + l15) * D_N + kg * 8;
    #pragma unroll
    for (int kk = 0; kk < 4; ++kk) {
        float4 v0 = *reinterpret_cast<const float4*>(ap + kk * 32);
        float4 v1 = *reinterpret_cast<const float4*>(ap + kk * 32 + 4);
        sq += v0.x*v0.x + v0.y*v0.y + v0.z*v0.z + v0.w*v0.w
            + v1.x*v1.x + v1.y*v1.y + v1.z*v1.z + v1.w*v1.w;
        a[kk] = cvt8(v0, v1);
    }
    sq += __shfl_xor(sq, 16);
    sq += __shfl_xor(sq, 32);
    float f2r[4]; int tg[4];
    #pragma unroll
    for (int r = 0; r < 4; ++r) {
        f2r[r] = __shfl(sq, kg * 4 + r);
        tg[r]  = tgt[row0 + kg * 4 + r];
    }

    float hsum = 0.f;
    #pragma unroll 4
    for (int i = 0; i < NB_TOT / 4; ++i) {
        const int nb = nb0 + i;
        const short8* bp =
            reinterpret_cast<const short8*>(bpre + (size_t)nb * 4 * 64 * 8) + lane;
        short8 b0 = bp[0];
        short8 b1 = bp[64];
        short8 b2 = bp[128];
        short8 b3 = bp[192];
        f32x4 acc = (f32x4){0.f, 0.f, 0.f, 0.f};
        acc = __builtin_amdgcn_mfma_f32_16x16x32_bf16(a[0], b0, acc, 0, 0, 0);
        acc = __builtin_amdgcn_mfma_f32_16x16x32_bf16(a[1], b1, acc, 0, 0, 0);
        acc = __builtin_amdgcn_mfma_f32_16x16x32_bf16(a[2], b2, acc, 0, 0, 0);
        acc = __builtin_amdgcn_mfma_f32_16x16x32_bf16(a[3], b3, acc, 0, 0, 0);
        // C/D layout: col = lane&15, row = kg*4 + r (verified m89).
        const int col   = nb * 16 + l15;
        const float c2v = c2p[col];
        #pragma unroll
        for (int r = 0; r < 4; ++r) {
            const float dist = f2r[r] + c2v - 2.0f * acc[r];
            float h = fmaxf(0.0f, MARGIN - dist);
            if (col >= C_N || col == tg[r]) h = 0.0f;
            hsum += h;
        }
    }
    hsum *= (1.0f / 16384.0f);
    #pragma unroll
    for (int off = 32; off; off >>= 1) hsum += __shfl_down(hsum, off);

    __shared__ float wsum[4];
    if (lane == 0) wsum[wave] = hsum;
    __syncthreads();
    if (tid == 0)
        part[blockIdx.y * gridDim.x + blockIdx.x] =
            wsum[0] + wsum[1] + wsum[2] + wsum[3];
}

// ---- kernel 3: reduce 1024 partials -> out[0] ----
__global__ __launch_bounds__(256) void reduce_kernel(
    const float* __restrict__ part, float* __restrict__ out)
{
    const int tid = threadIdx.x;
    float s = part[tid] + part[tid + 256] + part[tid + 512] + part[tid + 768];
    #pragma unroll
    for (int off = 32; off; off >>= 1) s += __shfl_down(s, off);
    __shared__ float ws[4];
    if ((tid & 63) == 0) ws[tid >> 6] = s;
    __syncthreads();
    if (tid == 0) out[0] = ws[0] + ws[1] + ws[2] + ws[3];
}

extern "C" void kernel_launch(void* const* d_in, const int* in_sizes, int n_in,
                              void* d_out, int out_size, void* d_ws, size_t ws_size,
                              hipStream_t stream) {
    const float* feat = (const float*)d_in[0];
    const int*   tgt  = (const int*)d_in[1];
    const float* cls  = (const float*)d_in[2];
    float*       out  = (float*)d_out;

    short* bpre = (short*)d_ws;                                   // 256 KiB
    float* c2p  = (float*)((char*)d_ws + (size_t)NB_TOT * 4 * 64 * 8 * sizeof(short));
    float* part = c2p + 1024;                                     // 4 KiB

    prep_kernel<<<64, 64, 0, stream>>>(cls, bpre, c2p);
    closs_kernel<<<dim3(4, 256), 256, 0, stream>>>(feat, tgt, bpre, c2p, part);
    reduce_kernel<<<1, 256, 0, stream>>>(part, out);
}